// Round 15
// baseline (153.542 us; speedup 1.0000x reference)
//
#include <hip/hip_runtime.h>

typedef __attribute__((ext_vector_type(8))) short short8;
typedef __attribute__((ext_vector_type(4))) float f32x4;

#define D128 128
#define TSTRIDE 132   // f32 row stride: 132%32==4 -> b128 readback conflict-free (R6-verified)

// fp32 -> bf16 round-to-nearest-even (bit pattern)
__device__ __forceinline__ unsigned short f2bf(float f) {
    unsigned int u = __float_as_uint(f);
    u += 0x7fffu + ((u >> 16) & 1u);
    return (unsigned short)(u >> 16);
}

// ---------------------------------------------------------------------------
// Pre-kernel (parallel): W (fp32 [k=128][col=128]) -> bf16 fragments in ws.
// wsb[(f*64+l)*8 + j] = bf16( w[(kk*32+(l>>4)*8+j)*128 + of*16 + (l&15)] ),
// f = of*4+kk. Used as the MFMA A-operand (swapped-operand layout).
// ---------------------------------------------------------------------------
__global__ __launch_bounds__(64)
void convert_w_kernel(const float* __restrict__ w, unsigned short* __restrict__ wsb) {
    int t  = blockIdx.x * 64 + threadIdx.x;  // 0..16383
    int f  = t >> 9;
    int l  = (t >> 3) & 63;
    int j  = t & 7;
    int of = f >> 2, kk = f & 3;
    int col = of * 16 + (l & 15);
    int k   = kk * 32 + (l >> 4) * 8 + j;
    wsb[t] = f2bf(w[k * D128 + col]);
}

// ---------------------------------------------------------------------------
// Main kernel — R14 structure (persistent grid, swapped-operand MFMA,
// 4-shuffle LN, per-wave LDS reshape, full-line 1KB NT wave-stores) with a
// VGPR diet for 4 waves/SIMD: bias reloaded from L1 per tile (frees 32
// VGPRs), __launch_bounds__(128,4) pins allocation at <=128. Grid doubled
// to 2048 persistent blocks -> 8 blocks/CU = 16 waves/CU = 2x in-flight
// store streams vs R14.
// ---------------------------------------------------------------------------
__global__ __launch_bounds__(128, 4)
void fused_linear_ln_kernel(const float* __restrict__ x,
                            const unsigned short* __restrict__ wsb,
                            const float* __restrict__ bias,
                            float* __restrict__ out,
                            int ntiles)
{
    __shared__ float tl[2][16][TSTRIDE];   // 16896 B: one 16x128(+pad) tile per wave

    const int tid  = threadIdx.x;
    const int lane = tid & 63;
    const int wave = tid >> 6;
    const int row  = lane & 15;    // x-row within wave tile (D col)
    const int g    = lane >> 4;    // 0..3: k-subgroup on load, out-feature subgroup
    const int gstride = gridDim.x;

    const int rsel = lane >> 5;          // 0/1 for readback/store
    const int c4   = (lane & 31) * 4;    // col start for readback/store

    // raw x buffer for the software pipeline
    float4 raw[4][2];

    // ---- prologue: issue loads for first tile ----
    {
        long rb = (long)blockIdx.x * 32 + wave * 16;
        const float* rp = x + (rb + row) * D128 + g * 8;
        #pragma unroll
        for (int kk = 0; kk < 4; ++kk) {
            const float4* p = (const float4*)(rp + kk * 32);
            raw[kk][0] = p[0];
            raw[kk][1] = p[1];
        }
    }

    for (int t = blockIdx.x; t < ntiles; t += gstride) {
        const long row_base = (long)t * 32 + wave * 16;

        // ---- cvt raw -> bf16 x fragments (MFMA B-operand) ----
        short8 xfrag[4];
        #pragma unroll
        for (int kk = 0; kk < 4; ++kk) {
            float4 v0 = raw[kk][0];
            float4 v1 = raw[kk][1];
            short8 a;
            a[0] = (short)f2bf(v0.x); a[1] = (short)f2bf(v0.y);
            a[2] = (short)f2bf(v0.z); a[3] = (short)f2bf(v0.w);
            a[4] = (short)f2bf(v1.x); a[5] = (short)f2bf(v1.y);
            a[6] = (short)f2bf(v1.z); a[7] = (short)f2bf(v1.w);
            xfrag[kk] = a;
        }

        // ---- issue next tile's loads (hidden under MFMA + epilogue) ----
        int tn = t + gstride;
        if (tn < ntiles) {
            long rb = (long)tn * 32 + wave * 16;
            const float* rp = x + (rb + row) * D128 + g * 8;
            #pragma unroll
            for (int kk = 0; kk < 4; ++kk) {
                const float4* p = (const float4*)(rp + kk * 32);
                raw[kk][0] = p[0];
                raw[kk][1] = p[1];
            }
        }

        // ---- MFMA: acc[of] = outs [of*16 + g*4 + r] of x-row `row` ----
        f32x4 acc[8];
        #pragma unroll
        for (int of = 0; of < 8; ++of) acc[of] = (f32x4){0.f, 0.f, 0.f, 0.f};

        #pragma unroll
        for (int kk = 0; kk < 4; ++kk) {
            short8 wfrag[8];
            #pragma unroll
            for (int of = 0; of < 8; ++of)
                wfrag[of] = *(const short8*)(wsb + (size_t)((of * 4 + kk) * 64 + lane) * 8);
            #pragma unroll
            for (int of = 0; of < 8; ++of)
                acc[of] = __builtin_amdgcn_mfma_f32_16x16x32_bf16(
                    wfrag[of], xfrag[kk], acc[of], 0, 0, 0);
        }

        // ---- single-pass epilogue: bias (L1 reload), 4-shuffle LN,
        //      normalize, LDS reshape, 8 full-line NT stores ----
        float s = 0.f, q = 0.f;
        #pragma unroll
        for (int of = 0; of < 8; ++of) {
            f32x4 b4 = *(const f32x4*)(bias + of * 16 + g * 4);   // L1-hot
            acc[of] += b4;
            #pragma unroll
            for (int r = 0; r < 4; ++r) {
                float z = acc[of][r];
                s += z;
                q += z * z;
            }
        }
        s += __shfl_xor(s, 16, 64);
        s += __shfl_xor(s, 32, 64);
        q += __shfl_xor(q, 16, 64);
        q += __shfl_xor(q, 32, 64);

        float mean = s * (1.0f / 128.0f);
        float var  = q * (1.0f / 128.0f) - mean * mean;
        float rs   = rsqrtf(var + 1e-5f);

        // normalize and scatter this lane's 8 f32x4 into its row
        #pragma unroll
        for (int of = 0; of < 8; ++of) {
            f32x4 v;
            #pragma unroll
            for (int r = 0; r < 4; ++r) v[r] = (acc[of][r] - mean) * rs;
            *(f32x4*)&tl[wave][row][of * 16 + g * 4] = v;
        }

        // readback row-major (conflict-free) + NT store (1KB full lines/instr)
        #pragma unroll
        for (int it = 0; it < 8; ++it) {
            int rr = 2 * it + rsel;
            f32x4 v = *(const f32x4*)&tl[wave][rr][c4];
            __builtin_nontemporal_store(
                v, (f32x4*)(out + (row_base + rr) * D128 + c4));
        }
    }
}

extern "C" void kernel_launch(void* const* d_in, const int* in_sizes, int n_in,
                              void* d_out, int out_size, void* d_ws, size_t ws_size,
                              hipStream_t stream) {
    const float* x    = (const float*)d_in[0];
    const float* w    = (const float*)d_in[1];
    const float* bias = (const float*)d_in[2];
    float* out        = (float*)d_out;

    int nrows  = in_sizes[0] / D128;   // 262144
    int ntiles = nrows / 32;           // 8192
    int grid   = 2048;                 // persistent: 8 blocks/CU, 4 tiles/block

    unsigned short* wsb = (unsigned short*)d_ws;
    hipLaunchKernelGGL(convert_w_kernel, dim3(256), dim3(64), 0, stream, w, wsb);
    hipLaunchKernelGGL(fused_linear_ln_kernel, dim3(grid), dim3(128), 0, stream,
                       x, wsb, bias, out, ntiles);
}

// Round 16
// 50.235 us; speedup vs baseline: 3.0565x; 3.0565x over previous
//
#include <hip/hip_runtime.h>

typedef __attribute__((ext_vector_type(8))) short short8;
typedef __attribute__((ext_vector_type(4))) float f32x4;

#define D128 128
#define TSTRIDE 132   // f32 row stride: 132%32==4 -> b128 readback conflict-free (R6-verified)

// fp32 -> bf16 round-to-nearest-even (bit pattern)
__device__ __forceinline__ unsigned short f2bf(float f) {
    unsigned int u = __float_as_uint(f);
    u += 0x7fffu + ((u >> 16) & 1u);
    return (unsigned short)(u >> 16);
}

// ---------------------------------------------------------------------------
// Pre-kernel (parallel): W (fp32 [k=128][col=128]) -> bf16 fragments in ws.
// wsb[(f*64+l)*8 + j] = bf16( w[(kk*32+(l>>4)*8+j)*128 + of*16 + (l&15)] ),
// f = of*4+kk. Used as the MFMA A-operand (swapped-operand layout).
// ---------------------------------------------------------------------------
__global__ __launch_bounds__(64)
void convert_w_kernel(const float* __restrict__ w, unsigned short* __restrict__ wsb) {
    int t  = blockIdx.x * 64 + threadIdx.x;  // 0..16383
    int f  = t >> 9;
    int l  = (t >> 3) & 63;
    int j  = t & 7;
    int of = f >> 2, kk = f & 3;
    int col = of * 16 + (l & 15);
    int k   = kk * 32 + (l >> 4) * 8 + j;
    wsb[t] = f2bf(w[k * D128 + col]);
}

// ---------------------------------------------------------------------------
// Main kernel — R14 structure exactly (persistent grid, swapped-operand
// MFMA, 4-shuffle LN, per-wave LDS reshape, full-line 1KB NT wave-stores),
// two deltas: (1) grid 1024 -> 2048 persistent blocks (R14 was GRID-limited
// to 8 waves/CU; VGPR allowed 12); (2) bias reloaded from L1 per tile
// (mild VGPR trim, NO forced launch_bounds min — R15's (128,4) made the
// allocator target 64 VGPR and spill 400MB of scratch).
// ---------------------------------------------------------------------------
__global__ __launch_bounds__(128)
void fused_linear_ln_kernel(const float* __restrict__ x,
                            const unsigned short* __restrict__ wsb,
                            const float* __restrict__ bias,
                            float* __restrict__ out,
                            int ntiles)
{
    __shared__ float tl[2][16][TSTRIDE];   // 16896 B: one 16x128(+pad) tile per wave

    const int tid  = threadIdx.x;
    const int lane = tid & 63;
    const int wave = tid >> 6;
    const int row  = lane & 15;    // x-row within wave tile (D col)
    const int g    = lane >> 4;    // 0..3: k-subgroup on load, out-feature subgroup
    const int gstride = gridDim.x;

    const int rsel = lane >> 5;          // 0/1 for readback/store
    const int c4   = (lane & 31) * 4;    // col start for readback/store

    // raw x buffer for the software pipeline
    float4 raw[4][2];

    // ---- prologue: issue loads for first tile ----
    {
        long rb = (long)blockIdx.x * 32 + wave * 16;
        const float* rp = x + (rb + row) * D128 + g * 8;
        #pragma unroll
        for (int kk = 0; kk < 4; ++kk) {
            const float4* p = (const float4*)(rp + kk * 32);
            raw[kk][0] = p[0];
            raw[kk][1] = p[1];
        }
    }

    for (int t = blockIdx.x; t < ntiles; t += gstride) {
        const long row_base = (long)t * 32 + wave * 16;

        // ---- cvt raw -> bf16 x fragments (MFMA B-operand) ----
        short8 xfrag[4];
        #pragma unroll
        for (int kk = 0; kk < 4; ++kk) {
            float4 v0 = raw[kk][0];
            float4 v1 = raw[kk][1];
            short8 a;
            a[0] = (short)f2bf(v0.x); a[1] = (short)f2bf(v0.y);
            a[2] = (short)f2bf(v0.z); a[3] = (short)f2bf(v0.w);
            a[4] = (short)f2bf(v1.x); a[5] = (short)f2bf(v1.y);
            a[6] = (short)f2bf(v1.z); a[7] = (short)f2bf(v1.w);
            xfrag[kk] = a;
        }

        // ---- issue next tile's loads (hidden under MFMA + epilogue) ----
        int tn = t + gstride;
        if (tn < ntiles) {
            long rb = (long)tn * 32 + wave * 16;
            const float* rp = x + (rb + row) * D128 + g * 8;
            #pragma unroll
            for (int kk = 0; kk < 4; ++kk) {
                const float4* p = (const float4*)(rp + kk * 32);
                raw[kk][0] = p[0];
                raw[kk][1] = p[1];
            }
        }

        // ---- MFMA: acc[of] = outs [of*16 + g*4 + r] of x-row `row` ----
        f32x4 acc[8];
        #pragma unroll
        for (int of = 0; of < 8; ++of) acc[of] = (f32x4){0.f, 0.f, 0.f, 0.f};

        #pragma unroll
        for (int kk = 0; kk < 4; ++kk) {
            short8 wfrag[8];
            #pragma unroll
            for (int of = 0; of < 8; ++of)
                wfrag[of] = *(const short8*)(wsb + (size_t)((of * 4 + kk) * 64 + lane) * 8);
            #pragma unroll
            for (int of = 0; of < 8; ++of)
                acc[of] = __builtin_amdgcn_mfma_f32_16x16x32_bf16(
                    wfrag[of], xfrag[kk], acc[of], 0, 0, 0);
        }

        // ---- single-pass epilogue: bias (L1 reload), 4-shuffle LN,
        //      normalize, LDS reshape, 8 full-line NT stores ----
        float s = 0.f, q = 0.f;
        #pragma unroll
        for (int of = 0; of < 8; ++of) {
            f32x4 b4 = *(const f32x4*)(bias + of * 16 + g * 4);   // L1-hot
            acc[of] += b4;
            #pragma unroll
            for (int r = 0; r < 4; ++r) {
                float z = acc[of][r];
                s += z;
                q += z * z;
            }
        }
        s += __shfl_xor(s, 16, 64);
        s += __shfl_xor(s, 32, 64);
        q += __shfl_xor(q, 16, 64);
        q += __shfl_xor(q, 32, 64);

        float mean = s * (1.0f / 128.0f);
        float var  = q * (1.0f / 128.0f) - mean * mean;
        float rs   = rsqrtf(var + 1e-5f);

        // normalize and scatter this lane's 8 f32x4 into its row
        #pragma unroll
        for (int of = 0; of < 8; ++of) {
            f32x4 v;
            #pragma unroll
            for (int r = 0; r < 4; ++r) v[r] = (acc[of][r] - mean) * rs;
            *(f32x4*)&tl[wave][row][of * 16 + g * 4] = v;
        }

        // readback row-major (conflict-free) + NT store (1KB full lines/instr)
        #pragma unroll
        for (int it = 0; it < 8; ++it) {
            int rr = 2 * it + rsel;
            f32x4 v = *(const f32x4*)&tl[wave][rr][c4];
            __builtin_nontemporal_store(
                v, (f32x4*)(out + (row_base + rr) * D128 + c4));
        }
    }
}

extern "C" void kernel_launch(void* const* d_in, const int* in_sizes, int n_in,
                              void* d_out, int out_size, void* d_ws, size_t ws_size,
                              hipStream_t stream) {
    const float* x    = (const float*)d_in[0];
    const float* w    = (const float*)d_in[1];
    const float* bias = (const float*)d_in[2];
    float* out        = (float*)d_out;

    int nrows  = in_sizes[0] / D128;   // 262144
    int ntiles = nrows / 32;           // 8192
    int grid   = 2048;                 // persistent: up to 8 blocks/CU, 4 tiles/block

    unsigned short* wsb = (unsigned short*)d_ws;
    hipLaunchKernelGGL(convert_w_kernel, dim3(256), dim3(64), 0, stream, w, wsb);
    hipLaunchKernelGGL(fused_linear_ln_kernel, dim3(grid), dim3(128), 0, stream,
                       x, wsb, bias, out, ntiles);
}